// Round 12
// baseline (2114.091 us; speedup 1.0000x reference)
//
#include <hip/hip_runtime.h>
#include <hip/hip_bf16.h>

typedef unsigned short u16;
typedef unsigned int   u32;

#define NN    32768
#define NG    512
#define TSEQ  64
#define NE    131072
#define NP    65536
#define HD    128

__device__ __forceinline__ float bf2f(u16 v){ u32 u=((u32)v)<<16; float f; __builtin_memcpy(&f,&u,4); return f; }
__device__ __forceinline__ u16 f2bf(float f){ u32 u; __builtin_memcpy(&u,&f,4); u32 r=u+0x7fffu+((u>>16)&1u); return (u16)(r>>16); }
__device__ __forceinline__ float sigm(float x){ return 1.f/(1.f+__expf(-x)); }
__device__ __forceinline__ float tanhfast(float x){ return 1.f-2.f/(1.f+__expf(2.f*x)); }
// raw-input read: dt=1 -> bf16, dt=0 -> fp32
__device__ __forceinline__ float rg(const void* p, size_t i, int dt){
  return dt ? bf2f(((const u16*)p)[i]) : ((const float*)p)[i];
}

// A-source modes / epilogues
enum { A_XF, A_F32, A_B16, A_MSG, A_C3, A_EDGE, A_BOOST };
enum { E_LN_RELU, E_LN, E_LN_RELU_TANH, E_RESID_LN, E_HE0_RELU, E_GI, E_LN_RELU_DUAL };

// ===== MEASURED-CONFIG LEDGER (do not re-try losers) =====
// dense core: 32-k W single-buffer SYNC stage is the proven kernel.
//   - reg double-buffer W (r5): -1.0ms REGRESSION. raw-bit uint4 (r6): -0.5ms.
//   - 128-row tiles (r8): WASH. NR=32 residency (r9): 2622->2126us. WIN.
//   - edge NR 64->32 (r11): 2126->2100us (residency curve flattening).
//   - A_C3G inline-gather (r10): FAILED (ws aliasing: gif/gib are 24MB each;
//     he must die before boost-GI in the <118MB proven map).
// r12: NSEG=2 dual-LN fuses init hv+hx2 (same A=X, staged ONCE; KC=160
//   chunk-free so A persists across segs). hx2 -> ws+120MB, guarded by
//   ws_size>=137MB with exact-r11 fallback. k_gather 256-thr/4-node.
// k_gru: 4 graphs/block, grid(128,2), launch_bounds(384,1) = BEST (318us).
//   - (384,3): spill -> 780us. next-step gi prefetch: spill -> 490us.
// ws map (r9, PROVEN): hv@6[6,22) he0@22[22,54) he@54[54,118)
//   mfin@22 | gif@54 gib@78 | oseq@6 | hv2@38 hx2@6(fallback) fout@54
//   gif_r@70 gib_r@94. Peak < 118MB. bigws: hx2@120[120,136).
// =========================================================

// Register-tiled fp32 GEMM core.
//  non-GI: NRT x 128 output tile, A in 64-k chunks (NSEG==2: single 160-k
//          chunk so A persists across 2 weight segments), W in 32-k
//          sub-chunks (16 KB), register epilogues (LN stats via 16-lane
//          shfl_xor butterfly over contiguous lanes).
//  GI:     64x128 tile, KC=128: A LDS-resident across NSEG=6 segments.
//  NSEG==2 (E_LN_RELU base): dual-LN — seg0: W/bias/gamma/beta -> outf
//          with ReLU; seg1: W2/bias2/a1v(gamma2)/a2v(beta2) ->
//          (float*)outb, no ReLU. prmoff==0 assumed for this variant.
// fp32 FMA in ascending k-order (sums bit-identical across tile geometry).
template<int AM, int EP, int NCH, int NSEG, int NRT>
__launch_bounds__(256)
__global__ void k_dense(
    const void* a0v, const void* a1v, const void* a2v,
    const int* dsti, const int* ptr, const int* cidx, const void* abias,
    const void* W, const void* W2, int wbase,
    const void* bias, const void* bias2, const void* gamma, const void* beta, int prmoff,
    const float* resid, const u16* he0b,
    float* outf, u16* outb, u16* outb2, const int* dflag,
    int ktot, int astride, int ostride, int ocoff)
{
  constexpr bool GI = (EP==E_GI);
  constexpr int NR  = NRT;              // output rows per block
  constexpr int KC  = GI ? 128 : (NSEG==2 ? 160 : 64);  // A k-chunk width
  constexpr int STR = KC + 4;           // sa row stride, 16B-aligned
  constexpr int MR  = NR/16;            // acc rows per thread

  __shared__ __align__(16) float sa[NR*STR];   // A tile
  __shared__ __align__(16) float wb[32*128];   // W sub-chunk [k][c], 16 KB
  __shared__ int s_e[NR], s_pe[NR], s_d[NR];
  __shared__ float s_ab[128];

  const int dt  = *dflag;
  const int tid = threadIdx.x;
  const int bx  = blockIdx.x;

  if constexpr (AM==A_EDGE){
    if (tid < NR){
      int eb = bx*(NR/2);
      int e  = (tid<NR/2) ? (eb+tid) : (NP + eb + tid - NR/2);
      s_e[tid]  = e;
      s_pe[tid] = (tid<NR/2) ? (e+NP) : (e-NP);
      s_d[tid]  = dsti[e];
    }
    __syncthreads();
  }
  if constexpr (AM==A_BOOST){
    if (tid < 128) s_ab[tid] = rg(abias, tid, dt);
    __syncthreads();
  }
  const int rbase = (AM==A_EDGE) ? 0 : bx*NR;

  const int ryb = (tid>>4)*MR;          // rows ryb..ryb+MR-1
  const int cxx = (tid&15)*4;           // cols cxx..+3 and 64+cxx..+3

  float acc[MR][8];

  for (int seg=0; seg<NSEG; ++seg){
    #pragma unroll
    for (int i=0;i<MR;i++)
      #pragma unroll
      for (int j=0;j<8;j++) acc[i][j]=0.f;

    const int wb_seg = (NSEG==6) ? (seg%3)*(ktot*HD) : wbase;
    const void* Wt   = (NSEG==6) ? (seg>=3 ? W2 : W)
                      : ((NSEG==2 && seg==1) ? W2 : W);
    const bool wvec = ((ktot&3)==0) && ((wb_seg&3)==0);

    for (int ch=0; ch<NCH; ++ch){
      int klim = ktot - ch*KC; if (klim > KC) klim = KC;

      if (seg==0){
        // ---- stage NRxKC fp32 A-chunk ----
        if constexpr (AM==A_XF){
          for (int idx=tid; idx<NR*KC; idx+=256){
            int r = idx/KC, lk = idx%KC, k = ch*KC + lk;
            float v = 0.f;
            if (k < ktot) v = rg(a0v, (size_t)(rbase+r)*astride + k, dt);
            sa[r*STR + lk] = v;
          }
        }
        if constexpr (AM==A_F32){
          for (int idx=tid; idx<NR*(KC/4); idx+=256){
            int r = idx/(KC/4), c4 = (idx%(KC/4))*4;
            float4 v = *(const float4*)((const float*)a0v + (size_t)(rbase+r)*astride + ch*KC + c4);
            *(float4*)&sa[r*STR + c4] = v;
          }
        }
        if constexpr (AM==A_B16){
          for (int idx=tid; idx<NR*(KC/4); idx+=256){
            int r = idx/(KC/4), c4 = (idx%(KC/4))*4;
            ushort4 u = *(const ushort4*)((const u16*)a0v + (size_t)(rbase+r)*astride + ch*KC + c4);
            *(float4*)&sa[r*STR + c4] = make_float4(bf2f(u.x),bf2f(u.y),bf2f(u.z),bf2f(u.w));
          }
        }
        if constexpr (AM==A_C3){
          const float* src = (ch<2)?(const float*)a0v:(ch<4)?(const float*)a1v:(const float*)a2v;
          const int coloff = (ch&1)*64;
          for (int idx=tid; idx<NR*(KC/4); idx+=256){
            int r = idx/(KC/4), c4 = (idx%(KC/4))*4;
            float4 v = *(const float4*)(src + (size_t)(rbase+r)*HD + coloff + c4);
            *(float4*)&sa[r*STR + c4] = v;
          }
        }
        if constexpr (AM==A_BOOST){
          for (int idx=tid; idx<NR*(KC/4); idx+=256){
            int r = idx/(KC/4), c4 = (idx%(KC/4))*4;
            float4 v = *(const float4*)((const float*)a0v + (size_t)(rbase+r)*HD + c4);
            v.x = fmaxf(v.x + s_ab[c4+0], 0.f);
            v.y = fmaxf(v.y + s_ab[c4+1], 0.f);
            v.z = fmaxf(v.z + s_ab[c4+2], 0.f);
            v.w = fmaxf(v.w + s_ab[c4+3], 0.f);
            *(float4*)&sa[r*STR + c4] = v;
          }
        }
        if constexpr (AM==A_EDGE){
          for (int idx=tid; idx<NR*(KC/4); idx+=256){
            int r = idx/(KC/4), c4 = (idx%(KC/4))*4;
            float4 va = *(const float4*)((const float*)a0v + (size_t)s_d[r]*HD + ch*KC + c4);
            float4 vb = *(const float4*)((const float*)a1v + (size_t)s_pe[r]*HD + ch*KC + c4);
            *(float4*)&sa[r*STR + c4] = make_float4(va.x-vb.x, va.y-vb.y, va.z-vb.z, va.w-vb.w);
          }
        }
        if constexpr (AM==A_MSG){
          if (ch < 2){
            for (int idx=tid; idx<NR*(KC/4); idx+=256){
              int r = idx/(KC/4), c4 = (idx%(KC/4))*4;
              float4 v = *(const float4*)((const float*)a0v + (size_t)(rbase+r)*HD + ch*KC + c4);
              *(float4*)&sa[r*STR + c4] = v;
            }
          } else {
            for (int idx=tid; idx<NR*KC; idx+=256){
              int r = idx/KC, lk = idx%KC;
              int cc = (ch-2)*KC + lk;
              int node = rbase+r;
              int b = ptr[node], en = ptr[node+1];
              float s=0.f, m=0.f;
              for (int i=b;i<en;++i){
                float t = ((const float*)a1v)[(size_t)cidx[i]*HD + cc];
                s += t; m = fmaxf(m,t);
              }
              sa[r*STR + lk] = s*m;   // m_sum * relu(segment_max); he>=0
            }
          }
        }
      }

      for (int kk=0; kk<klim; kk+=32){
        // ---- stage W sub-chunk [32 k][128 c]; thread: c=tid>>1, k-half=(tid&1)*16 ----
        {
          int c = tid>>1, kh = (tid&1)*16;
          size_t wrow = (size_t)wb_seg + (size_t)c*ktot + (size_t)ch*KC + kk;
          if (wvec && dt==0){
            const float* Wf = (const float*)Wt;
            #pragma unroll
            for (int j4=0;j4<4;j4++){
              int kq = kh + j4*4;
              float v0=0.f,v1=0.f,v2=0.f,v3=0.f;
              if (kk+kq+4 <= klim){
                float4 v = *(const float4*)(Wf + wrow + kq);
                v0=v.x; v1=v.y; v2=v.z; v3=v.w;
              } else if (kk+kq < klim){
                v0 = Wf[wrow+kq];
                if (kk+kq+1<klim) v1 = Wf[wrow+kq+1];
                if (kk+kq+2<klim) v2 = Wf[wrow+kq+2];
              }
              wb[(kq+0)*128+c]=v0; wb[(kq+1)*128+c]=v1; wb[(kq+2)*128+c]=v2; wb[(kq+3)*128+c]=v3;
            }
          } else if (wvec){
            const u16* Wh = (const u16*)Wt;
            #pragma unroll
            for (int j4=0;j4<4;j4++){
              int kq = kh + j4*4;
              float v0=0.f,v1=0.f,v2=0.f,v3=0.f;
              if (kk+kq+4 <= klim){
                ushort4 v = *(const ushort4*)(Wh + wrow + kq);
                v0=bf2f(v.x); v1=bf2f(v.y); v2=bf2f(v.z); v3=bf2f(v.w);
              } else if (kk+kq < klim){
                v0 = bf2f(Wh[wrow+kq]);
                if (kk+kq+1<klim) v1 = bf2f(Wh[wrow+kq+1]);
                if (kk+kq+2<klim) v2 = bf2f(Wh[wrow+kq+2]);
              }
              wb[(kq+0)*128+c]=v0; wb[(kq+1)*128+c]=v1; wb[(kq+2)*128+c]=v2; wb[(kq+3)*128+c]=v3;
            }
          } else {
            for (int j=0;j<16;j++){
              int kq = kh + j;
              wb[kq*128+c] = (kk+kq < klim) ? rg(Wt, wrow+kq, dt) : 0.f;
            }
          }
        }
        __syncthreads();   // sa (if staged this round) + wb ready

        // ---- compute: 32 k's, zero-padded tails contribute 0 ----
        for (int kc=0; kc<32; kc+=4){
          float4 aa[MR];
          #pragma unroll
          for (int i=0;i<MR;i++)
            aa[i] = *(const float4*)&sa[(ryb+i)*STR + kk + kc];
          #pragma unroll
          for (int t=0;t<4;t++){
            float4 b0 = *(const float4*)&wb[(kc+t)*128 + cxx];
            float4 b1 = *(const float4*)&wb[(kc+t)*128 + 64 + cxx];
            #pragma unroll
            for (int i=0;i<MR;i++){
              float a = (t==0)?aa[i].x:(t==1)?aa[i].y:(t==2)?aa[i].z:aa[i].w;
              acc[i][0]+=a*b0.x; acc[i][1]+=a*b0.y; acc[i][2]+=a*b0.z; acc[i][3]+=a*b0.w;
              acc[i][4]+=a*b1.x; acc[i][5]+=a*b1.y; acc[i][6]+=a*b1.z; acc[i][7]+=a*b1.w;
            }
          }
        }
        __syncthreads();   // before restaging wb / next A chunk
      }
    }

    if constexpr (EP==E_GI){
      // register epilogue: out = f2bf(acc + bias), packed ushort4 stores
      const void* bsrc = (NSEG==6 && seg>=3) ? bias2 : bias;
      const int   po   = (NSEG==6) ? (seg%3)*HD : prmoff;
      u16*        op   = (NSEG==6) ? (seg<3 ? outb : outb2) : outb;
      const int   oc   = (NSEG==6) ? (seg%3)*HD : ocoff;
      float b0[4], b1[4];
      #pragma unroll
      for (int j=0;j<4;j++){
        b0[j] = rg(bsrc, po + cxx + j, dt);
        b1[j] = rg(bsrc, po + 64 + cxx + j, dt);
      }
      #pragma unroll
      for (int i=0;i<MR;i++){
        size_t gr = (size_t)(rbase + ryb + i);
        ushort4 u0, u1;
        u0.x=f2bf(acc[i][0]+b0[0]); u0.y=f2bf(acc[i][1]+b0[1]);
        u0.z=f2bf(acc[i][2]+b0[2]); u0.w=f2bf(acc[i][3]+b0[3]);
        u1.x=f2bf(acc[i][4]+b1[0]); u1.y=f2bf(acc[i][5]+b1[1]);
        u1.z=f2bf(acc[i][6]+b1[2]); u1.w=f2bf(acc[i][7]+b1[3]);
        *(ushort4*)&op[gr*ostride + oc + cxx]      = u0;
        *(ushort4*)&op[gr*ostride + oc + 64 + cxx] = u1;
      }
    }

    if constexpr (NSEG==2){
      // dual-LN epilogue (prmoff==0): seg0 -> outf (ReLU); seg1 ->
      // (float*)outb via gamma2=a1v / beta2=a2v / bias2 (no ReLU).
      const void* bsrc = seg ? bias2 : bias;
      const void* gsrc = seg ? a1v   : gamma;
      const void* tsrc = seg ? a2v   : beta;
      float*      osrc = seg ? (float*)outb : outf;
      float bc[8], gc[8], tc[8];
      #pragma unroll
      for (int j=0;j<4;j++){
        bc[j]   = rg(bsrc, cxx + j,      dt);
        bc[4+j] = rg(bsrc, 64 + cxx + j, dt);
        gc[j]   = rg(gsrc, cxx + j,      dt);
        gc[4+j] = rg(gsrc, 64 + cxx + j, dt);
        tc[j]   = rg(tsrc, cxx + j,      dt);
        tc[4+j] = rg(tsrc, 64 + cxx + j, dt);
      }
      #pragma unroll
      for (int i=0;i<MR;i++){
        size_t grow = (size_t)(rbase + ryb + i);
        #pragma unroll
        for (int j=0;j<8;j++) acc[i][j] += bc[j];
        float sm=0.f, sq=0.f;
        #pragma unroll
        for (int j=0;j<8;j++){ sm += acc[i][j]; sq += acc[i][j]*acc[i][j]; }
        sm += __shfl_xor(sm,1); sq += __shfl_xor(sq,1);
        sm += __shfl_xor(sm,2); sq += __shfl_xor(sq,2);
        sm += __shfl_xor(sm,4); sq += __shfl_xor(sq,4);
        sm += __shfl_xor(sm,8); sq += __shfl_xor(sq,8);
        float mu  = sm*(1.f/128.f);
        float var = sq*(1.f/128.f) - mu*mu;
        float rs  = rsqrtf(fmaxf(var,0.f)+1e-5f);
        float y[8];
        #pragma unroll
        for (int j=0;j<8;j++){
          float v = (acc[i][j]-mu)*rs*gc[j] + tc[j];
          if (seg==0) v = fmaxf(v,0.f);
          y[j] = v;
        }
        *(float4*)&osrc[grow*HD + cxx]      = make_float4(y[0],y[1],y[2],y[3]);
        *(float4*)&osrc[grow*HD + 64 + cxx] = make_float4(y[4],y[5],y[6],y[7]);
      }
    }
  }

  if constexpr (EP==E_GI || NSEG==2) return;

  // ================= register epilogues (no LDS C round-trip) =================
  if constexpr (EP==E_HE0_RELU){
    float b0[4], b1[4];
    #pragma unroll
    for (int j=0;j<4;j++){
      b0[j] = rg(bias, prmoff + cxx + j, dt);
      b1[j] = rg(bias, prmoff + 64 + cxx + j, dt);
    }
    #pragma unroll
    for (int i=0;i<MR;i++){
      int e = s_e[ryb+i];
      ushort4 h0 = *(const ushort4*)&he0b[(size_t)e*HD + cxx];
      ushort4 h1 = *(const ushort4*)&he0b[(size_t)e*HD + 64 + cxx];
      float4 o0, o1;
      o0.x = fmaxf(acc[i][0]+b0[0]+bf2f(h0.x), 0.f);
      o0.y = fmaxf(acc[i][1]+b0[1]+bf2f(h0.y), 0.f);
      o0.z = fmaxf(acc[i][2]+b0[2]+bf2f(h0.z), 0.f);
      o0.w = fmaxf(acc[i][3]+b0[3]+bf2f(h0.w), 0.f);
      o1.x = fmaxf(acc[i][4]+b1[0]+bf2f(h1.x), 0.f);
      o1.y = fmaxf(acc[i][5]+b1[1]+bf2f(h1.y), 0.f);
      o1.z = fmaxf(acc[i][6]+b1[2]+bf2f(h1.z), 0.f);
      o1.w = fmaxf(acc[i][7]+b1[3]+bf2f(h1.w), 0.f);
      *(float4*)&outf[(size_t)e*HD + cxx]      = o0;
      *(float4*)&outf[(size_t)e*HD + 64 + cxx] = o1;
    }
    return;
  }
  // LayerNorm family: bias/resid folded into acc, row stats via 16-lane
  // shfl_xor butterfly (row-group threads are contiguous lanes).
  {
    float bc[8], gc[8], tc[8];
    #pragma unroll
    for (int j=0;j<4;j++){
      bc[j]   = rg(bias,  prmoff + cxx + j,      dt);
      bc[4+j] = rg(bias,  prmoff + 64 + cxx + j, dt);
      gc[j]   = rg(gamma, prmoff + cxx + j,      dt);
      gc[4+j] = rg(gamma, prmoff + 64 + cxx + j, dt);
      tc[j]   = rg(beta,  prmoff + cxx + j,      dt);
      tc[4+j] = rg(beta,  prmoff + 64 + cxx + j, dt);
    }
    #pragma unroll
    for (int i=0;i<MR;i++){
      size_t grow = (size_t)(rbase + ryb + i);
      if constexpr (EP==E_RESID_LN){
        float4 r0 = *(const float4*)&resid[grow*HD + cxx];
        float4 r1 = *(const float4*)&resid[grow*HD + 64 + cxx];
        acc[i][0] = r0.x + fmaxf(acc[i][0]+bc[0], 0.f);
        acc[i][1] = r0.y + fmaxf(acc[i][1]+bc[1], 0.f);
        acc[i][2] = r0.z + fmaxf(acc[i][2]+bc[2], 0.f);
        acc[i][3] = r0.w + fmaxf(acc[i][3]+bc[3], 0.f);
        acc[i][4] = r1.x + fmaxf(acc[i][4]+bc[4], 0.f);
        acc[i][5] = r1.y + fmaxf(acc[i][5]+bc[5], 0.f);
        acc[i][6] = r1.z + fmaxf(acc[i][6]+bc[6], 0.f);
        acc[i][7] = r1.w + fmaxf(acc[i][7]+bc[7], 0.f);
      } else {
        #pragma unroll
        for (int j=0;j<8;j++) acc[i][j] += bc[j];
      }
      float sm=0.f, sq=0.f;
      #pragma unroll
      for (int j=0;j<8;j++){ sm += acc[i][j]; sq += acc[i][j]*acc[i][j]; }
      sm += __shfl_xor(sm,1); sq += __shfl_xor(sq,1);
      sm += __shfl_xor(sm,2); sq += __shfl_xor(sq,2);
      sm += __shfl_xor(sm,4); sq += __shfl_xor(sq,4);
      sm += __shfl_xor(sm,8); sq += __shfl_xor(sq,8);
      float mu  = sm*(1.f/128.f);
      float var = sq*(1.f/128.f) - mu*mu;
      float rs  = rsqrtf(fmaxf(var,0.f)+1e-5f);
      float y[8];
      #pragma unroll
      for (int j=0;j<8;j++){
        float v = (acc[i][j]-mu)*rs*gc[j] + tc[j];
        if constexpr (EP==E_LN_RELU || EP==E_LN_RELU_DUAL) v = fmaxf(v,0.f);
        if constexpr (EP==E_LN_RELU_TANH) v = tanhfast(fmaxf(v,0.f));
        y[j] = v;
      }
      *(float4*)&outf[grow*HD + cxx]      = make_float4(y[0],y[1],y[2],y[3]);
      *(float4*)&outf[grow*HD + 64 + cxx] = make_float4(y[4],y[5],y[6],y[7]);
      if constexpr (EP==E_LN_RELU_DUAL){
        ushort4 u0, u1;
        u0.x=f2bf(y[0]); u0.y=f2bf(y[1]); u0.z=f2bf(y[2]); u0.w=f2bf(y[3]);
        u1.x=f2bf(y[4]); u1.y=f2bf(y[5]); u1.z=f2bf(y[6]); u1.w=f2bf(y[7]);
        *(ushort4*)&outb[grow*HD + cxx]      = u0;
        *(ushort4*)&outb[grow*HD + 64 + cxx] = u1;
      }
    }
  }
}

// merged weight pre-convert: 4 (whh,bhh) pairs raw -> fp32 [49152|384] blocks
__global__ void k_cvt4(const void* w0,const void* b0,const void* w1,const void* b1,
                       const void* w2,const void* b2,const void* w3,const void* b3,
                       float* d0, float* d1, float* d2, float* d3, const int* dflag){
  int dt = *dflag;
  int p  = blockIdx.y;
  const void* wsrc = (p==0)?w0:(p==1)?w1:(p==2)?w2:w3;
  const void* bsrc = (p==0)?b0:(p==1)?b1:(p==2)?b2:b3;
  float* dst       = (p==0)?d0:(p==1)?d1:(p==2)?d2:d3;
  int i = blockIdx.x*256 + threadIdx.x;
  if (i < 49152)      dst[i] = rg(wsrc, i, dt);
  else if (i < 49536) dst[i] = rg(bsrc, i-49152, dt);
}

// BiGRU, W-in-registers (EXACT r6-measured 318us config — do not touch).
__launch_bounds__(384,1)
__global__ void k_gru(
  const u16* gi_f, const u16* gi_b,
  const float* wcf, const float* wcb,
  u16* out_seq, float* zbuf, int write_seq)
{
  const int dir = blockIdx.y;
  const int g0  = blockIdx.x * 4;
  const u16* gi  = dir ? gi_b : gi_f;
  const float* whh = dir ? wcb : wcf;
  const float* bh  = whh + 49152;

  __shared__ float sgh[384*5];               // [row d][graph g], stride 5
  __shared__ __align__(16) float sh[4*128];  // h state [g][d]

  const int tid = threadIdx.x;   // 0..383, owns gate-row d=tid

  float4 wreg[32];
  {
    const float4* wrow = (const float4*)(whh + (size_t)tid*128);
    #pragma unroll
    for (int i=0;i<32;i++) wreg[i] = wrow[i];
  }
  const float bhd = bh[tid];

  const int gA = tid>>7, dA = tid&127;

  for (int i=tid;i<512;i+=384) sh[i]=0.f;
  __syncthreads();

  for (int step=0; step<64; ++step){
    const int t = dir ? (63-step) : step;

    const u16* gpA = gi + (size_t)((g0+gA)*TSEQ + t)*384;
    u16 aR = gpA[dA], aZ = gpA[128+dA], aN = gpA[256+dA];
    u16 bR=0, bZ=0, bN=0;
    if (tid < 128){
      const u16* gpB = gi + (size_t)((g0+3)*TSEQ + t)*384;
      bR = gpB[tid]; bZ = gpB[128+tid]; bN = gpB[256+tid];
    }

    float a0=0.f, a1=0.f, a2=0.f, a3=0.f;
    #pragma unroll
    for (int k4=0; k4<32; k4++){
      float4 w  = wreg[k4];
      float4 h0 = *(const float4*)&sh[0*128 + k4*4];
      float4 h1 = *(const float4*)&sh[1*128 + k4*4];
      float4 h2 = *(const float4*)&sh[2*128 + k4*4];
      float4 h3 = *(const float4*)&sh[3*128 + k4*4];
      a0 += h0.x*w.x + h0.y*w.y + h0.z*w.z + h0.w*w.w;
      a1 += h1.x*w.x + h1.y*w.y + h1.z*w.z + h1.w*w.w;
      a2 += h2.x*w.x + h2.y*w.y + h2.z*w.z + h2.w*w.w;
      a3 += h3.x*w.x + h3.y*w.y + h3.z*w.z + h3.w*w.w;
    }
    sgh[tid*5+0] = a0 + bhd;
    sgh[tid*5+1] = a1 + bhd;
    sgh[tid*5+2] = a2 + bhd;
    sgh[tid*5+3] = a3 + bhd;
    __syncthreads();

    {
      float r = sigm(bf2f(aR) + sgh[dA*5+gA]);
      float z = sigm(bf2f(aZ) + sgh[(128+dA)*5+gA]);
      float n = tanhfast(bf2f(aN) + r*sgh[(256+dA)*5+gA]);
      float h = (1.f-z)*n + z*sh[gA*128+dA];
      sh[gA*128+dA] = h;
      if (write_seq){
        float hc = fminf(fmaxf(h,-10.f),10.f);
        out_seq[(size_t)((g0+gA)*TSEQ + t)*256 + dir*HD + dA] = f2bf(hc);
      }
    }
    if (tid < 128){
      float r = sigm(bf2f(bR) + sgh[tid*5+3]);
      float z = sigm(bf2f(bZ) + sgh[(128+tid)*5+3]);
      float n = tanhfast(bf2f(bN) + r*sgh[(256+tid)*5+3]);
      float h = (1.f-z)*n + z*sh[3*128+tid];
      sh[3*128+tid] = h;
      if (write_seq){
        float hc = fminf(fmaxf(h,-10.f),10.f);
        out_seq[(size_t)((g0+3)*TSEQ + t)*256 + dir*HD + tid] = f2bf(hc);
      }
    }
    __syncthreads();
  }

  if (!write_seq){
    for (int i=tid;i<512;i+=384){
      int g=i>>7, d=i&127;
      zbuf[(size_t)(g0+g)*256 + dir*HD + d] = fminf(fmaxf(sh[g*128+d],-10.f),10.f);
    }
  }
}

// 4 nodes/block (256 threads), same per-node CSR order as before
__launch_bounds__(256)
__global__ void k_gather(const float* he, const int* ptr, const int* cidx, float* out){
  int n = blockIdx.x*4 + (threadIdx.x>>6);
  int c = threadIdx.x & 63;
  int b = ptr[n], e = ptr[n+1];
  float s0=0.f,s1=0.f;
  for (int i=b;i<e;++i){
    int eid = cidx[i];
    float2 v = *(const float2*)(he + (size_t)eid*HD + c*2);
    s0+=v.x; s1+=v.y;
  }
  out[(size_t)n*HD + c*2]   = s0;
  out[(size_t)n*HD + c*2+1] = s1;
}

__global__ void k_count(const int* dst, int* cnt){
  int e = blockIdx.x*256+threadIdx.x;
  if (e<NE) atomicAdd(&cnt[dst[e]],1);
}

__launch_bounds__(1024)
__global__ void k_scan(const int* cnt, int* ptr){
  __shared__ int s[1024];
  int tid=threadIdx.x;
  int loc[32]; int tot=0;
  int base = tid*32;
  #pragma unroll
  for (int i=0;i<32;i++){ loc[i]=tot; tot += cnt[base+i]; }
  s[tid]=tot; __syncthreads();
  for (int off=1; off<1024; off<<=1){
    int v = (tid>=off)? s[tid-off] : 0;
    __syncthreads();
    s[tid] += v;
    __syncthreads();
  }
  int ex = s[tid] - tot;
  for (int i=0;i<32;i++) ptr[base+i] = ex + loc[i];
  if (tid==1023) ptr[NN] = ex + tot;
}

__global__ void k_fill(const int* dst, const int* ptr, int* cur, int* cidx){
  int e = blockIdx.x*256+threadIdx.x;
  if (e<NE){
    int d = dst[e];
    int p = ptr[d] + atomicAdd(&cur[d],1);
    cidx[p] = e;
  }
}

// runtime input-dtype detector (fp32 low-halfword exponents ~uniform; bf16 ~always in-range)
__global__ void k_detect(const u16* x, int* flag){
  __shared__ int cnt;
  if (threadIdx.x==0) cnt=0;
  __syncthreads();
  u16 u = x[threadIdx.x*2];
  int e = (u>>7)&0xff;
  if (e>=100 && e<=135) atomicAdd(&cnt,1);
  __syncthreads();
  if (threadIdx.x==0) *flag = (cnt>=128) ? 1 : 0;
}

__launch_bounds__(256)
__global__ void k_bnstats(const float* z, const void* bng, const void* bnb, float* st, const int* dflag){
  int dt = *dflag;
  int c = threadIdx.x;
  float sm=0.f, sq=0.f;
  for (int g=0; g<NG; ++g){ float v = z[(size_t)g*256+c]; sm+=v; sq+=v*v; }
  float mu = sm*(1.f/(float)NG);
  float var = sq*(1.f/(float)NG) - mu*mu;
  float rs = rsqrtf(fmaxf(var,0.f)+1e-5f);
  float sc = rs*rg(bng,c,dt);
  st[c] = sc;
  st[256+c] = rg(bnb,c,dt) - mu*sc;
}

// OUTPUT fp32 (confirmed: finite ref-scale error under fp32 writes)
__global__ void k_pred(const float* z, const float* st, const void* pw, const void* pb, float* out, const int* dflag){
  int dt = *dflag;
  int g = blockIdx.x*256+threadIdx.x;
  if (g>=NG) return;
  float acc = rg(pb,0,dt);
  for (int c=0;c<256;c++) acc += (z[(size_t)g*256+c]*st[c] + st[256+c])*rg(pw,c,dt);
  out[g]=acc;
}

extern "C" void kernel_launch(void* const* d_in, const int* in_sizes, int n_in,
                              void* d_out, int out_size, void* d_ws, size_t ws_size,
                              hipStream_t stream)
{
  const void* X    =d_in[0];
  const void* EA   =d_in[1];
  const void* NW   =d_in[2];
  const void* NB   =d_in[3];
  const void* NGa  =d_in[4];
  const void* NBt  =d_in[5];
  const void* EW   =d_in[6];
  const void* EB   =d_in[7];
  const void* EGa  =d_in[8];
  const void* EBt  =d_in[9];
  const void* LW   =d_in[10];
  const void* LB   =d_in[11];
  const void* LGa  =d_in[12];
  const void* LBt  =d_in[13];
  const void* NUW  =d_in[14];
  const void* NUB  =d_in[15];
  const void* NNG  =d_in[16];
  const void* NNB  =d_in[17];
  const void* EUW  =d_in[18];
  const void* EUB  =d_in[19];
  const void* BOOST=d_in[20];
  const void* BIHW_F=d_in[21];
  const void* BHHW_F=d_in[22];
  const void* BIHB_F=d_in[23];
  const void* BHHB_F=d_in[24];
  const void* BIHW_B=d_in[25];
  const void* BHHW_B=d_in[26];
  const void* BIHB_B=d_in[27];
  const void* BHHB_B=d_in[28];
  const void* PW   =d_in[29];
  const void* PB   =d_in[30];
  const void* PG   =d_in[31];
  const void* PBt  =d_in[32];
  const void* FW   =d_in[33];
  const void* FB   =d_in[34];
  const void* FG   =d_in[35];
  const void* FBt  =d_in[36];
  const void* RIHW_F=d_in[37];
  const void* RHHW_F=d_in[38];
  const void* RIHB_F=d_in[39];
  const void* RHHB_F=d_in[40];
  const void* RIHW_B=d_in[41];
  const void* RHHW_B=d_in[42];
  const void* RIHB_B=d_in[43];
  const void* RHHB_B=d_in[44];
  const void* BNG  =d_in[45];
  const void* BNB  =d_in[46];
  const void* PRW  =d_in[47];
  const void* PRB  =d_in[48];
  const int* EIDX =(const int*)d_in[49];
  const int* DST  = EIDX + NE;

  // ---- Workspace (EXACT r9 proven map; peak < 118MB).
  //      bigws (>=137MB): hx2 lives at [120,136) so it can be written at
  //      init (fused dual-LN) and survive until the final merge. ----
  char* ws=(char*)d_ws;
  const size_t MB = 1048576;
  int*   csrp =(int*)  (ws + 0);
  int*   csrc =(int*)  (ws + 135168);
  int*   csri =(int*)  (ws + 266240);
  float* zbuf =(float*)(ws + 790528);
  float* stats=(float*)(ws + 1314816);
  int*   dflag=(int*)  (ws + 1316864);
  float* wbgf =(float*)(ws + 2*MB);          // [49152 whh | 384 bhh] fp32, boost fwd
  float* wbgb = wbgf + 49536;                // boost bwd
  float* wrgf = wbgb + 49536;                // readout fwd
  float* wrgb = wrgf + 49536;                // readout bwd
  float* hv   =(float*)(ws + 6*MB);          // [6,22)
  u16*   he0  =(u16*)  (ws + 22*MB);         // [22,54), dead after last edge
  float* he   =(float*)(ws + 54*MB);         // [54,118), dead after k_gather
  float* mfin =(float*)(ws + 22*MB);         // aliases he0 (dead)
  u16*   gif  =(u16*)  (ws + 54*MB);         // aliases he (dead), [54,78)
  u16*   gib  =(u16*)  (ws + 78*MB);         // [78,102)
  u16*   oseq =(u16*)  (ws + 6*MB);          // aliases hv (dead after boost-GI)
  float* hv2  =(float*)(ws + 38*MB);         // [38,54)
  float* fout =(float*)(ws + 54*MB);         // aliases gif (dead), [54,70)
  u16*   gif_r=(u16*)  (ws + 70*MB);         // [70,94)
  u16*   gib_r=(u16*)  (ws + 94*MB);         // [94,118)

  const bool bigws = (ws_size >= (size_t)137*MB);
  float* hx2 = bigws ? (float*)(ws + 120*MB)   // [120,136): survives init->merge
                     : (float*)(ws + 6*MB);    // fallback: computed just before merge

  k_detect<<<dim3(1),dim3(256),0,stream>>>((const u16*)X, dflag);

  // pre-convert recurrent GRU weights to fp32 (one merged launch)
  k_cvt4<<<dim3(194,4),dim3(256),0,stream>>>(
      BHHW_F,BHHB_F, BHHW_B,BHHB_B, RHHW_F,RHHB_F, RHHW_B,RHHB_B,
      wbgf, wbgb, wrgf, wrgb, dflag);

  // CSR over dst
  hipMemsetAsync(csrc, 0, 131072, stream);
  k_count<<<dim3(512),dim3(256),0,stream>>>(DST, csrc);
  k_scan<<<dim3(1),dim3(1024),0,stream>>>(csrc, csrp);
  hipMemsetAsync(csrc, 0, 131072, stream);
  k_fill<<<dim3(512),dim3(256),0,stream>>>(DST, csrp, csrc, csri);

  // init embeddings
  if (bigws){
    // fused dual-LN: X staged ONCE -> hv (NW, LN+ReLU) and hx2 (LW, LN)
    k_dense<A_XF,E_LN_RELU,1,2,32><<<dim3(1024),dim3(256),0,stream>>>(X,LGa,LBt,
        nullptr,nullptr,nullptr,nullptr, NW,LW,0, NB,LB,NGa,NBt,0, nullptr,nullptr,
        hv,(u16*)hx2,nullptr, dflag, 133,133,HD,0);
  } else {
    k_dense<A_XF,E_LN_RELU,3,1,32><<<dim3(1024),dim3(256),0,stream>>>(X,nullptr,nullptr,
        nullptr,nullptr,nullptr,nullptr, NW,nullptr,0, NB,nullptr,NGa,NBt,0, nullptr,nullptr,
        hv,nullptr,nullptr, dflag, 133,133,HD,0);
  }
  k_dense<A_XF,E_LN_RELU_DUAL,1,1,32><<<dim3(4096),dim3(256),0,stream>>>(EA,nullptr,nullptr,
      nullptr,nullptr,nullptr,nullptr, EW,nullptr,0, EB,nullptr,EGa,EBt,0, nullptr,nullptr,
      he,he0,nullptr, dflag, 14,14,HD,0);

  // message passing (msg: 32-row; edge: 32-row -> ~6 blocks/CU)
  for (int s=0;s<5;s++){
    k_dense<A_MSG,E_RESID_LN,4,1,32><<<dim3(1024),dim3(256),0,stream>>>(hv,he,nullptr,
        nullptr,csrp,csri,nullptr, NUW,nullptr,s*32768, NUB,nullptr,NNG,NNB,s*128,
        hv,nullptr, hv,nullptr,nullptr, dflag, 256,HD,HD,0);
    k_dense<A_EDGE,E_HE0_RELU,2,1,32><<<dim3(4096),dim3(256),0,stream>>>(hv,he,nullptr,
        DST,nullptr,nullptr,nullptr, EUW,nullptr,s*16384, EUB,nullptr,nullptr,nullptr,s*128,
        nullptr,he0, he,nullptr,nullptr, dflag, 128,HD,HD,0);
  }
  k_gather<<<dim3(NN/4),dim3(256),0,stream>>>(he, csrp, csri, mfin);

  // boost GRU input-side gates: ONE launch, 6 weight segments (frozen geometry)
  k_dense<A_BOOST,E_GI,1,6,64><<<dim3(512),dim3(256),0,stream>>>(hv,nullptr,nullptr,
      nullptr,nullptr,nullptr,BOOST, BIHW_F,BIHW_B,0, BIHB_F,BIHB_B,nullptr,nullptr,0,
      nullptr,nullptr, nullptr,gif,gib, dflag, 128,HD,384,0);
  k_gru<<<dim3(128,2),dim3(384),0,stream>>>(gif, gib, wbgf, wbgb, oseq, zbuf, 1);

  // proj + (hx2 if not fused) + final merge (32-row LN tiles)
  k_dense<A_B16,E_LN_RELU_TANH,4,1,32><<<dim3(1024),dim3(256),0,stream>>>(oseq,nullptr,nullptr,
      nullptr,nullptr,nullptr,nullptr, PW,nullptr,0, PB,nullptr,PG,PBt,0, nullptr,nullptr,
      hv2,nullptr,nullptr, dflag, 256,256,HD,0);
  if (!bigws){
    k_dense<A_XF,E_LN,3,1,32><<<dim3(1024),dim3(256),0,stream>>>(X,nullptr,nullptr,
        nullptr,nullptr,nullptr,nullptr, LW,nullptr,0, LB,nullptr,LGa,LBt,0, nullptr,nullptr,
        hx2,nullptr,nullptr, dflag, 133,133,HD,0);
  }
  k_dense<A_C3,E_LN_RELU,6,1,32><<<dim3(1024),dim3(256),0,stream>>>(hv2,mfin,hx2,
      nullptr,nullptr,nullptr,nullptr, FW,nullptr,0, FB,nullptr,FG,FBt,0, nullptr,nullptr,
      fout,nullptr,nullptr, dflag, 384,HD,HD,0);

  // readout GRU gates (ONE launch, 6 segments) + GRU
  k_dense<A_F32,E_GI,1,6,64><<<dim3(512),dim3(256),0,stream>>>(fout,nullptr,nullptr,
      nullptr,nullptr,nullptr,nullptr, RIHW_F,RIHW_B,0, RIHB_F,RIHB_B,nullptr,nullptr,0,
      nullptr,nullptr, nullptr,gif_r,gib_r, dflag, 128,HD,384,0);
  k_gru<<<dim3(128,2),dim3(384),0,stream>>>(gif_r, gib_r, wrgf, wrgb, oseq, zbuf, 0);

  // BN + prediction
  k_bnstats<<<dim3(1),dim3(256),0,stream>>>(zbuf, BNG, BNB, stats, dflag);
  k_pred<<<dim3(2),dim3(256),0,stream>>>(zbuf, stats, PRW, PRB, (float*)d_out, dflag);

  (void)in_sizes; (void)n_in; (void)out_size;
}

// Round 13
// 2030.876 us; speedup vs baseline: 1.0410x; 1.0410x over previous
//
#include <hip/hip_runtime.h>
#include <hip/hip_bf16.h>

typedef unsigned short u16;
typedef unsigned int   u32;

#define NN    32768
#define NG    512
#define TSEQ  64
#define NE    131072
#define NP    65536
#define HD    128

__device__ __forceinline__ float bf2f(u16 v){ u32 u=((u32)v)<<16; float f; __builtin_memcpy(&f,&u,4); return f; }
__device__ __forceinline__ u16 f2bf(float f){ u32 u; __builtin_memcpy(&u,&f,4); u32 r=u+0x7fffu+((u>>16)&1u); return (u16)(r>>16); }
__device__ __forceinline__ float sigm(float x){ return 1.f/(1.f+__expf(-x)); }
__device__ __forceinline__ float tanhfast(float x){ return 1.f-2.f/(1.f+__expf(2.f*x)); }
// raw-input read: dt=1 -> bf16, dt=0 -> fp32
__device__ __forceinline__ float rg(const void* p, size_t i, int dt){
  return dt ? bf2f(((const u16*)p)[i]) : ((const float*)p)[i];
}
// wave-broadcast: lane 'l' (compile-time literal) -> SGPR operand
__device__ __forceinline__ float rdl(float v, int l){
  return __uint_as_float(__builtin_amdgcn_readlane(__float_as_uint(v), l));
}

// A-source modes / epilogues
enum { A_XF, A_F32, A_B16, A_MSG, A_C3, A_EDGE, A_BOOST };
enum { E_LN_RELU, E_LN, E_LN_RELU_TANH, E_RESID_LN, E_HE0_RELU, E_GI, E_LN_RELU_DUAL };

// ===== MEASURED-CONFIG LEDGER (do not re-try losers) =====
// dense core: 32-k W single-buffer SYNC stage is the proven kernel.
//   - reg double-buffer W (r5): -1.0ms REGRESSION. raw-bit uint4 (r6): -0.5ms.
//   - 128-row tiles (r8): WASH. NR=32 residency (r9): 2622->2126us. WIN.
//   - edge NR 64->32 (r11): small win. dual-LN + gather-batch (r12): WASH.
//   - A_C3G inline-gather (r10): FAILED (ws aliasing).
// k_gru ladder: scalar-W 2.26ms -> W-in-reg 4-graph 318us (r6). r13: the
//   318us config is LDS-BROADCAST BOUND (6 waves x 128 ds_read_b128/step =
//   ~9.2K LDS-cyc/step ~ measured). Fix: per-lane h slice (8 ds_read_b32)
//   + v_readlane broadcast in the GEMV -> LDS traffic ~150x down, GEMV on
//   VALU. Watch for r5-style silent spill (VGPR=128 + WRITE_SIZE>30MB).
// ws map (r9, PROVEN): hv@6[6,22) he0@22[22,54) he@54[54,118)
//   mfin@22 | gif@54 gib@78 | oseq@6 | hv2@38 hx2@6(fallback) fout@54
//   gif_r@70 gib_r@94. Peak < 118MB. bigws: hx2@120[120,136).
// =========================================================

// Register-tiled fp32 GEMM core (unchanged from r12).
template<int AM, int EP, int NCH, int NSEG, int NRT>
__launch_bounds__(256)
__global__ void k_dense(
    const void* a0v, const void* a1v, const void* a2v,
    const int* dsti, const int* ptr, const int* cidx, const void* abias,
    const void* W, const void* W2, int wbase,
    const void* bias, const void* bias2, const void* gamma, const void* beta, int prmoff,
    const float* resid, const u16* he0b,
    float* outf, u16* outb, u16* outb2, const int* dflag,
    int ktot, int astride, int ostride, int ocoff)
{
  constexpr bool GI = (EP==E_GI);
  constexpr int NR  = NRT;              // output rows per block
  constexpr int KC  = GI ? 128 : (NSEG==2 ? 160 : 64);  // A k-chunk width
  constexpr int STR = KC + 4;           // sa row stride, 16B-aligned
  constexpr int MR  = NR/16;            // acc rows per thread

  __shared__ __align__(16) float sa[NR*STR];   // A tile
  __shared__ __align__(16) float wb[32*128];   // W sub-chunk [k][c], 16 KB
  __shared__ int s_e[NR], s_pe[NR], s_d[NR];
  __shared__ float s_ab[128];

  const int dt  = *dflag;
  const int tid = threadIdx.x;
  const int bx  = blockIdx.x;

  if constexpr (AM==A_EDGE){
    if (tid < NR){
      int eb = bx*(NR/2);
      int e  = (tid<NR/2) ? (eb+tid) : (NP + eb + tid - NR/2);
      s_e[tid]  = e;
      s_pe[tid] = (tid<NR/2) ? (e+NP) : (e-NP);
      s_d[tid]  = dsti[e];
    }
    __syncthreads();
  }
  if constexpr (AM==A_BOOST){
    if (tid < 128) s_ab[tid] = rg(abias, tid, dt);
    __syncthreads();
  }
  const int rbase = (AM==A_EDGE) ? 0 : bx*NR;

  const int ryb = (tid>>4)*MR;          // rows ryb..ryb+MR-1
  const int cxx = (tid&15)*4;           // cols cxx..+3 and 64+cxx..+3

  float acc[MR][8];

  for (int seg=0; seg<NSEG; ++seg){
    #pragma unroll
    for (int i=0;i<MR;i++)
      #pragma unroll
      for (int j=0;j<8;j++) acc[i][j]=0.f;

    const int wb_seg = (NSEG==6) ? (seg%3)*(ktot*HD) : wbase;
    const void* Wt   = (NSEG==6) ? (seg>=3 ? W2 : W)
                      : ((NSEG==2 && seg==1) ? W2 : W);
    const bool wvec = ((ktot&3)==0) && ((wb_seg&3)==0);

    for (int ch=0; ch<NCH; ++ch){
      int klim = ktot - ch*KC; if (klim > KC) klim = KC;

      if (seg==0){
        // ---- stage NRxKC fp32 A-chunk ----
        if constexpr (AM==A_XF){
          for (int idx=tid; idx<NR*KC; idx+=256){
            int r = idx/KC, lk = idx%KC, k = ch*KC + lk;
            float v = 0.f;
            if (k < ktot) v = rg(a0v, (size_t)(rbase+r)*astride + k, dt);
            sa[r*STR + lk] = v;
          }
        }
        if constexpr (AM==A_F32){
          for (int idx=tid; idx<NR*(KC/4); idx+=256){
            int r = idx/(KC/4), c4 = (idx%(KC/4))*4;
            float4 v = *(const float4*)((const float*)a0v + (size_t)(rbase+r)*astride + ch*KC + c4);
            *(float4*)&sa[r*STR + c4] = v;
          }
        }
        if constexpr (AM==A_B16){
          for (int idx=tid; idx<NR*(KC/4); idx+=256){
            int r = idx/(KC/4), c4 = (idx%(KC/4))*4;
            ushort4 u = *(const ushort4*)((const u16*)a0v + (size_t)(rbase+r)*astride + ch*KC + c4);
            *(float4*)&sa[r*STR + c4] = make_float4(bf2f(u.x),bf2f(u.y),bf2f(u.z),bf2f(u.w));
          }
        }
        if constexpr (AM==A_C3){
          const float* src = (ch<2)?(const float*)a0v:(ch<4)?(const float*)a1v:(const float*)a2v;
          const int coloff = (ch&1)*64;
          for (int idx=tid; idx<NR*(KC/4); idx+=256){
            int r = idx/(KC/4), c4 = (idx%(KC/4))*4;
            float4 v = *(const float4*)(src + (size_t)(rbase+r)*HD + coloff + c4);
            *(float4*)&sa[r*STR + c4] = v;
          }
        }
        if constexpr (AM==A_BOOST){
          for (int idx=tid; idx<NR*(KC/4); idx+=256){
            int r = idx/(KC/4), c4 = (idx%(KC/4))*4;
            float4 v = *(const float4*)((const float*)a0v + (size_t)(rbase+r)*HD + c4);
            v.x = fmaxf(v.x + s_ab[c4+0], 0.f);
            v.y = fmaxf(v.y + s_ab[c4+1], 0.f);
            v.z = fmaxf(v.z + s_ab[c4+2], 0.f);
            v.w = fmaxf(v.w + s_ab[c4+3], 0.f);
            *(float4*)&sa[r*STR + c4] = v;
          }
        }
        if constexpr (AM==A_EDGE){
          for (int idx=tid; idx<NR*(KC/4); idx+=256){
            int r = idx/(KC/4), c4 = (idx%(KC/4))*4;
            float4 va = *(const float4*)((const float*)a0v + (size_t)s_d[r]*HD + ch*KC + c4);
            float4 vb = *(const float4*)((const float*)a1v + (size_t)s_pe[r]*HD + ch*KC + c4);
            *(float4*)&sa[r*STR + c4] = make_float4(va.x-vb.x, va.y-vb.y, va.z-vb.z, va.w-vb.w);
          }
        }
        if constexpr (AM==A_MSG){
          if (ch < 2){
            for (int idx=tid; idx<NR*(KC/4); idx+=256){
              int r = idx/(KC/4), c4 = (idx%(KC/4))*4;
              float4 v = *(const float4*)((const float*)a0v + (size_t)(rbase+r)*HD + ch*KC + c4);
              *(float4*)&sa[r*STR + c4] = v;
            }
          } else {
            for (int idx=tid; idx<NR*KC; idx+=256){
              int r = idx/KC, lk = idx%KC;
              int cc = (ch-2)*KC + lk;
              int node = rbase+r;
              int b = ptr[node], en = ptr[node+1];
              float s=0.f, m=0.f;
              for (int i=b;i<en;++i){
                float t = ((const float*)a1v)[(size_t)cidx[i]*HD + cc];
                s += t; m = fmaxf(m,t);
              }
              sa[r*STR + lk] = s*m;   // m_sum * relu(segment_max); he>=0
            }
          }
        }
      }

      for (int kk=0; kk<klim; kk+=32){
        // ---- stage W sub-chunk [32 k][128 c]; thread: c=tid>>1, k-half=(tid&1)*16 ----
        {
          int c = tid>>1, kh = (tid&1)*16;
          size_t wrow = (size_t)wb_seg + (size_t)c*ktot + (size_t)ch*KC + kk;
          if (wvec && dt==0){
            const float* Wf = (const float*)Wt;
            #pragma unroll
            for (int j4=0;j4<4;j4++){
              int kq = kh + j4*4;
              float v0=0.f,v1=0.f,v2=0.f,v3=0.f;
              if (kk+kq+4 <= klim){
                float4 v = *(const float4*)(Wf + wrow + kq);
                v0=v.x; v1=v.y; v2=v.z; v3=v.w;
              } else if (kk+kq < klim){
                v0 = Wf[wrow+kq];
                if (kk+kq+1<klim) v1 = Wf[wrow+kq+1];
                if (kk+kq+2<klim) v2 = Wf[wrow+kq+2];
              }
              wb[(kq+0)*128+c]=v0; wb[(kq+1)*128+c]=v1; wb[(kq+2)*128+c]=v2; wb[(kq+3)*128+c]=v3;
            }
          } else if (wvec){
            const u16* Wh = (const u16*)Wt;
            #pragma unroll
            for (int j4=0;j4<4;j4++){
              int kq = kh + j4*4;
              float v0=0.f,v1=0.f,v2=0.f,v3=0.f;
              if (kk+kq+4 <= klim){
                ushort4 v = *(const ushort4*)(Wh + wrow + kq);
                v0=bf2f(v.x); v1=bf2f(v.y); v2=bf2f(v.z); v3=bf2f(v.w);
              } else if (kk+kq < klim){
                v0 = bf2f(Wh[wrow+kq]);
                if (kk+kq+1<klim) v1 = bf2f(Wh[wrow+kq+1]);
                if (kk+kq+2<klim) v2 = bf2f(Wh[wrow+kq+2]);
              }
              wb[(kq+0)*128+c]=v0; wb[(kq+1)*128+c]=v1; wb[(kq+2)*128+c]=v2; wb[(kq+3)*128+c]=v3;
            }
          } else {
            for (int j=0;j<16;j++){
              int kq = kh + j;
              wb[kq*128+c] = (kk+kq < klim) ? rg(Wt, wrow+kq, dt) : 0.f;
            }
          }
        }
        __syncthreads();   // sa (if staged this round) + wb ready

        // ---- compute: 32 k's, zero-padded tails contribute 0 ----
        for (int kc=0; kc<32; kc+=4){
          float4 aa[MR];
          #pragma unroll
          for (int i=0;i<MR;i++)
            aa[i] = *(const float4*)&sa[(ryb+i)*STR + kk + kc];
          #pragma unroll
          for (int t=0;t<4;t++){
            float4 b0 = *(const float4*)&wb[(kc+t)*128 + cxx];
            float4 b1 = *(const float4*)&wb[(kc+t)*128 + 64 + cxx];
            #pragma unroll
            for (int i=0;i<MR;i++){
              float a = (t==0)?aa[i].x:(t==1)?aa[i].y:(t==2)?aa[i].z:aa[i].w;
              acc[i][0]+=a*b0.x; acc[i][1]+=a*b0.y; acc[i][2]+=a*b0.z; acc[i][3]+=a*b0.w;
              acc[i][4]+=a*b1.x; acc[i][5]+=a*b1.y; acc[i][6]+=a*b1.z; acc[i][7]+=a*b1.w;
            }
          }
        }
        __syncthreads();   // before restaging wb / next A chunk
      }
    }

    if constexpr (EP==E_GI){
      // register epilogue: out = f2bf(acc + bias), packed ushort4 stores
      const void* bsrc = (NSEG==6 && seg>=3) ? bias2 : bias;
      const int   po   = (NSEG==6) ? (seg%3)*HD : prmoff;
      u16*        op   = (NSEG==6) ? (seg<3 ? outb : outb2) : outb;
      const int   oc   = (NSEG==6) ? (seg%3)*HD : ocoff;
      float b0[4], b1[4];
      #pragma unroll
      for (int j=0;j<4;j++){
        b0[j] = rg(bsrc, po + cxx + j, dt);
        b1[j] = rg(bsrc, po + 64 + cxx + j, dt);
      }
      #pragma unroll
      for (int i=0;i<MR;i++){
        size_t gr = (size_t)(rbase + ryb + i);
        ushort4 u0, u1;
        u0.x=f2bf(acc[i][0]+b0[0]); u0.y=f2bf(acc[i][1]+b0[1]);
        u0.z=f2bf(acc[i][2]+b0[2]); u0.w=f2bf(acc[i][3]+b0[3]);
        u1.x=f2bf(acc[i][4]+b1[0]); u1.y=f2bf(acc[i][5]+b1[1]);
        u1.z=f2bf(acc[i][6]+b1[2]); u1.w=f2bf(acc[i][7]+b1[3]);
        *(ushort4*)&op[gr*ostride + oc + cxx]      = u0;
        *(ushort4*)&op[gr*ostride + oc + 64 + cxx] = u1;
      }
    }

    if constexpr (NSEG==2){
      // dual-LN epilogue (prmoff==0): seg0 -> outf (ReLU); seg1 ->
      // (float*)outb via gamma2=a1v / beta2=a2v / bias2 (no ReLU).
      const void* bsrc = seg ? bias2 : bias;
      const void* gsrc = seg ? a1v   : gamma;
      const void* tsrc = seg ? a2v   : beta;
      float*      osrc = seg ? (float*)outb : outf;
      float bc[8], gc[8], tc[8];
      #pragma unroll
      for (int j=0;j<4;j++){
        bc[j]   = rg(bsrc, cxx + j,      dt);
        bc[4+j] = rg(bsrc, 64 + cxx + j, dt);
        gc[j]   = rg(gsrc, cxx + j,      dt);
        gc[4+j] = rg(gsrc, 64 + cxx + j, dt);
        tc[j]   = rg(tsrc, cxx + j,      dt);
        tc[4+j] = rg(tsrc, 64 + cxx + j, dt);
      }
      #pragma unroll
      for (int i=0;i<MR;i++){
        size_t grow = (size_t)(rbase + ryb + i);
        #pragma unroll
        for (int j=0;j<8;j++) acc[i][j] += bc[j];
        float sm=0.f, sq=0.f;
        #pragma unroll
        for (int j=0;j<8;j++){ sm += acc[i][j]; sq += acc[i][j]*acc[i][j]; }
        sm += __shfl_xor(sm,1); sq += __shfl_xor(sq,1);
        sm += __shfl_xor(sm,2); sq += __shfl_xor(sq,2);
        sm += __shfl_xor(sm,4); sq += __shfl_xor(sq,4);
        sm += __shfl_xor(sm,8); sq += __shfl_xor(sq,8);
        float mu  = sm*(1.f/128.f);
        float var = sq*(1.f/128.f) - mu*mu;
        float rs  = rsqrtf(fmaxf(var,0.f)+1e-5f);
        float y[8];
        #pragma unroll
        for (int j=0;j<8;j++){
          float v = (acc[i][j]-mu)*rs*gc[j] + tc[j];
          if (seg==0) v = fmaxf(v,0.f);
          y[j] = v;
        }
        *(float4*)&osrc[grow*HD + cxx]      = make_float4(y[0],y[1],y[2],y[3]);
        *(float4*)&osrc[grow*HD + 64 + cxx] = make_float4(y[4],y[5],y[6],y[7]);
      }
    }
  }

  if constexpr (EP==E_GI || NSEG==2) return;

  // ================= register epilogues (no LDS C round-trip) =================
  if constexpr (EP==E_HE0_RELU){
    float b0[4], b1[4];
    #pragma unroll
    for (int j=0;j<4;j++){
      b0[j] = rg(bias, prmoff + cxx + j, dt);
      b1[j] = rg(bias, prmoff + 64 + cxx + j, dt);
    }
    #pragma unroll
    for (int i=0;i<MR;i++){
      int e = s_e[ryb+i];
      ushort4 h0 = *(const ushort4*)&he0b[(size_t)e*HD + cxx];
      ushort4 h1 = *(const ushort4*)&he0b[(size_t)e*HD + 64 + cxx];
      float4 o0, o1;
      o0.x = fmaxf(acc[i][0]+b0[0]+bf2f(h0.x), 0.f);
      o0.y = fmaxf(acc[i][1]+b0[1]+bf2f(h0.y), 0.f);
      o0.z = fmaxf(acc[i][2]+b0[2]+bf2f(h0.z), 0.f);
      o0.w = fmaxf(acc[i][3]+b0[3]+bf2f(h0.w), 0.f);
      o1.x = fmaxf(acc[i][4]+b1[0]+bf2f(h1.x), 0.f);
      o1.y = fmaxf(acc[i][5]+b1[1]+bf2f(h1.y), 0.f);
      o1.z = fmaxf(acc[i][6]+b1[2]+bf2f(h1.z), 0.f);
      o1.w = fmaxf(acc[i][7]+b1[3]+bf2f(h1.w), 0.f);
      *(float4*)&outf[(size_t)e*HD + cxx]      = o0;
      *(float4*)&outf[(size_t)e*HD + 64 + cxx] = o1;
    }
    return;
  }
  // LayerNorm family: bias/resid folded into acc, row stats via 16-lane
  // shfl_xor butterfly (row-group threads are contiguous lanes).
  {
    float bc[8], gc[8], tc[8];
    #pragma unroll
    for (int j=0;j<4;j++){
      bc[j]   = rg(bias,  prmoff + cxx + j,      dt);
      bc[4+j] = rg(bias,  prmoff + 64 + cxx + j, dt);
      gc[j]   = rg(gamma, prmoff + cxx + j,      dt);
      gc[4+j] = rg(gamma, prmoff + 64 + cxx + j, dt);
      tc[j]   = rg(beta,  prmoff + cxx + j,      dt);
      tc[4+j] = rg(beta,  prmoff + 64 + cxx + j, dt);
    }
    #pragma unroll
    for (int i=0;i<MR;i++){
      size_t grow = (size_t)(rbase + ryb + i);
      if constexpr (EP==E_RESID_LN){
        float4 r0 = *(const float4*)&resid[grow*HD + cxx];
        float4 r1 = *(const float4*)&resid[grow*HD + 64 + cxx];
        acc[i][0] = r0.x + fmaxf(acc[i][0]+bc[0], 0.f);
        acc[i][1] = r0.y + fmaxf(acc[i][1]+bc[1], 0.f);
        acc[i][2] = r0.z + fmaxf(acc[i][2]+bc[2], 0.f);
        acc[i][3] = r0.w + fmaxf(acc[i][3]+bc[3], 0.f);
        acc[i][4] = r1.x + fmaxf(acc[i][4]+bc[4], 0.f);
        acc[i][5] = r1.y + fmaxf(acc[i][5]+bc[5], 0.f);
        acc[i][6] = r1.z + fmaxf(acc[i][6]+bc[6], 0.f);
        acc[i][7] = r1.w + fmaxf(acc[i][7]+bc[7], 0.f);
      } else {
        #pragma unroll
        for (int j=0;j<8;j++) acc[i][j] += bc[j];
      }
      float sm=0.f, sq=0.f;
      #pragma unroll
      for (int j=0;j<8;j++){ sm += acc[i][j]; sq += acc[i][j]*acc[i][j]; }
      sm += __shfl_xor(sm,1); sq += __shfl_xor(sq,1);
      sm += __shfl_xor(sm,2); sq += __shfl_xor(sq,2);
      sm += __shfl_xor(sm,4); sq += __shfl_xor(sq,4);
      sm += __shfl_xor(sm,8); sq += __shfl_xor(sq,8);
      float mu  = sm*(1.f/128.f);
      float var = sq*(1.f/128.f) - mu*mu;
      float rs  = rsqrtf(fmaxf(var,0.f)+1e-5f);
      float y[8];
      #pragma unroll
      for (int j=0;j<8;j++){
        float v = (acc[i][j]-mu)*rs*gc[j] + tc[j];
        if constexpr (EP==E_LN_RELU || EP==E_LN_RELU_DUAL) v = fmaxf(v,0.f);
        if constexpr (EP==E_LN_RELU_TANH) v = tanhfast(fmaxf(v,0.f));
        y[j] = v;
      }
      *(float4*)&outf[grow*HD + cxx]      = make_float4(y[0],y[1],y[2],y[3]);
      *(float4*)&outf[grow*HD + 64 + cxx] = make_float4(y[4],y[5],y[6],y[7]);
      if constexpr (EP==E_LN_RELU_DUAL){
        ushort4 u0, u1;
        u0.x=f2bf(y[0]); u0.y=f2bf(y[1]); u0.z=f2bf(y[2]); u0.w=f2bf(y[3]);
        u1.x=f2bf(y[4]); u1.y=f2bf(y[5]); u1.z=f2bf(y[6]); u1.w=f2bf(y[7]);
        *(ushort4*)&outb[grow*HD + cxx]      = u0;
        *(ushort4*)&outb[grow*HD + 64 + cxx] = u1;
      }
    }
  }
}

// merged weight pre-convert: 4 (whh,bhh) pairs raw -> fp32 [49152|384] blocks
__global__ void k_cvt4(const void* w0,const void* b0,const void* w1,const void* b1,
                       const void* w2,const void* b2,const void* w3,const void* b3,
                       float* d0, float* d1, float* d2, float* d3, const int* dflag){
  int dt = *dflag;
  int p  = blockIdx.y;
  const void* wsrc = (p==0)?w0:(p==1)?w1:(p==2)?w2:w3;
  const void* bsrc = (p==0)?b0:(p==1)?b1:(p==2)?b2:b3;
  float* dst       = (p==0)?d0:(p==1)?d1:(p==2)?d2:d3;
  int i = blockIdx.x*256 + threadIdx.x;
  if (i < 49152)      dst[i] = rg(wsrc, i, dt);
  else if (i < 49536) dst[i] = rg(bsrc, i-49152, dt);
}

// BiGRU r13: W-in-registers + per-lane h slice + v_readlane broadcast.
// 4 graphs x one dir per block (grid 128x2). Thread owns gate-row d=tid
// (whh row in 32 float4 = 128 VGPR). Per step each thread loads only ITS
// 8 h values (conflict-free ds_read_b32); the GEMV broadcasts h[k] via
// v_readlane (SGPR operand) instead of 128 redundant ds_read_b128/wave —
// removes the LDS-broadcast bottleneck of the r6 config (318us).
// fp32 math; summation regrouped (readlane order) — within threshold.
__launch_bounds__(384,1)
__global__ void k_gru(
  const u16* gi_f, const u16* gi_b,
  const float* wcf, const float* wcb,
  u16* out_seq, float* zbuf, int write_seq)
{
  const int dir = blockIdx.y;
  const int g0  = blockIdx.x * 4;
  const u16* gi  = dir ? gi_b : gi_f;
  const float* whh = dir ? wcb : wcf;
  const float* bh  = whh + 49152;

  __shared__ float sgh[384*5];               // [row d][graph g], stride 5
  __shared__ __align__(16) float sh[4*128];  // h state [g][d]

  const int tid  = threadIdx.x;   // 0..383, owns gate-row d=tid
  const int lane = tid & 63;

  float4 wreg[32];
  {
    const float4* wrow = (const float4*)(whh + (size_t)tid*128);
    #pragma unroll
    for (int i=0;i<32;i++) wreg[i] = wrow[i];
  }
  const float bhd = bh[tid];

  const int gA = tid>>7, dA = tid&127;

  for (int i=tid;i<512;i+=384) sh[i]=0.f;
  __syncthreads();

  for (int step=0; step<64; ++step){
    const int t = dir ? (63-step) : step;

    // gi prefetch (global; hides under the GEMV)
    const u16* gpA = gi + (size_t)((g0+gA)*TSEQ + t)*384;
    u16 aR = gpA[dA], aZ = gpA[128+dA], aN = gpA[256+dA];
    u16 bR=0, bZ=0, bN=0;
    if (tid < 128){
      const u16* gpB = gi + (size_t)((g0+3)*TSEQ + t)*384;
      bR = gpB[tid]; bZ = gpB[128+tid]; bN = gpB[256+tid];
    }

    // per-lane h slice: 8 conflict-free ds_read_b32 (lane-consecutive)
    float h00 = sh[      lane], h01 = sh[ 64+lane];
    float h10 = sh[128 + lane], h11 = sh[192+lane];
    float h20 = sh[256 + lane], h21 = sh[320+lane];
    float h30 = sh[384 + lane], h31 = sh[448+lane];

    // GEMV via readlane broadcast: gh[d][g] = whh[d]·h[g]
    float a0=0.f, a1=0.f, a2=0.f, a3=0.f;
    #pragma unroll
    for (int k4=0;k4<16;k4++){
      const float4 wlo = wreg[k4];        // w[k4*4 .. +3]
      const float4 whi = wreg[16+k4];     // w[64+k4*4 .. +3]
      const int kb = k4*4;
      a0 += rdl(h00,kb+0)*wlo.x + rdl(h00,kb+1)*wlo.y + rdl(h00,kb+2)*wlo.z + rdl(h00,kb+3)*wlo.w;
      a0 += rdl(h01,kb+0)*whi.x + rdl(h01,kb+1)*whi.y + rdl(h01,kb+2)*whi.z + rdl(h01,kb+3)*whi.w;
      a1 += rdl(h10,kb+0)*wlo.x + rdl(h10,kb+1)*wlo.y + rdl(h10,kb+2)*wlo.z + rdl(h10,kb+3)*wlo.w;
      a1 += rdl(h11,kb+0)*whi.x + rdl(h11,kb+1)*whi.y + rdl(h11,kb+2)*whi.z + rdl(h11,kb+3)*whi.w;
      a2 += rdl(h20,kb+0)*wlo.x + rdl(h20,kb+1)*wlo.y + rdl(h20,kb+2)*wlo.z + rdl(h20,kb+3)*wlo.w;
      a2 += rdl(h21,kb+0)*whi.x + rdl(h21,kb+1)*whi.y + rdl(h21,kb+2)*whi.z + rdl(h21,kb+3)*whi.w;
      a3 += rdl(h30,kb+0)*wlo.x + rdl(h30,kb+1)*wlo.y + rdl(h30,kb+2)*wlo.z + rdl(h30,kb+3)*wlo.w;
      a3 += rdl(h31,kb+0)*whi.x + rdl(h31,kb+1)*whi.y + rdl(h31,kb+2)*whi.z + rdl(h31,kb+3)*whi.w;
    }
    sgh[tid*5+0] = a0 + bhd;
    sgh[tid*5+1] = a1 + bhd;
    sgh[tid*5+2] = a2 + bhd;
    sgh[tid*5+3] = a3 + bhd;
    __syncthreads();

    // ---- cell update (unchanged) ----
    {
      float r = sigm(bf2f(aR) + sgh[dA*5+gA]);
      float z = sigm(bf2f(aZ) + sgh[(128+dA)*5+gA]);
      float n = tanhfast(bf2f(aN) + r*sgh[(256+dA)*5+gA]);
      float h = (1.f-z)*n + z*sh[gA*128+dA];
      sh[gA*128+dA] = h;
      if (write_seq){
        float hc = fminf(fmaxf(h,-10.f),10.f);
        out_seq[(size_t)((g0+gA)*TSEQ + t)*256 + dir*HD + dA] = f2bf(hc);
      }
    }
    if (tid < 128){
      float r = sigm(bf2f(bR) + sgh[tid*5+3]);
      float z = sigm(bf2f(bZ) + sgh[(128+tid)*5+3]);
      float n = tanhfast(bf2f(bN) + r*sgh[(256+tid)*5+3]);
      float h = (1.f-z)*n + z*sh[3*128+tid];
      sh[3*128+tid] = h;
      if (write_seq){
        float hc = fminf(fmaxf(h,-10.f),10.f);
        out_seq[(size_t)((g0+3)*TSEQ + t)*256 + dir*HD + tid] = f2bf(hc);
      }
    }
    __syncthreads();
  }

  if (!write_seq){
    for (int i=tid;i<512;i+=384){
      int g=i>>7, d=i&127;
      zbuf[(size_t)(g0+g)*256 + dir*HD + d] = fminf(fmaxf(sh[g*128+d],-10.f),10.f);
    }
  }
}

// 4 nodes/block (256 threads), same per-node CSR order as before
__launch_bounds__(256)
__global__ void k_gather(const float* he, const int* ptr, const int* cidx, float* out){
  int n = blockIdx.x*4 + (threadIdx.x>>6);
  int c = threadIdx.x & 63;
  int b = ptr[n], e = ptr[n+1];
  float s0=0.f,s1=0.f;
  for (int i=b;i<e;++i){
    int eid = cidx[i];
    float2 v = *(const float2*)(he + (size_t)eid*HD + c*2);
    s0+=v.x; s1+=v.y;
  }
  out[(size_t)n*HD + c*2]   = s0;
  out[(size_t)n*HD + c*2+1] = s1;
}

__global__ void k_count(const int* dst, int* cnt){
  int e = blockIdx.x*256+threadIdx.x;
  if (e<NE) atomicAdd(&cnt[dst[e]],1);
}

__launch_bounds__(1024)
__global__ void k_scan(const int* cnt, int* ptr){
  __shared__ int s[1024];
  int tid=threadIdx.x;
  int loc[32]; int tot=0;
  int base = tid*32;
  #pragma unroll
  for (int i=0;i<32;i++){ loc[i]=tot; tot += cnt[base+i]; }
  s[tid]=tot; __syncthreads();
  for (int off=1; off<1024; off<<=1){
    int v = (tid>=off)? s[tid-off] : 0;
    __syncthreads();
    s[tid] += v;
    __syncthreads();
  }
  int ex = s[tid] - tot;
  for (int i=0;i<32;i++) ptr[base+i] = ex + loc[i];
  if (tid==1023) ptr[NN] = ex + tot;
}

__global__ void k_fill(const int* dst, const int* ptr, int* cur, int* cidx){
  int e = blockIdx.x*256+threadIdx.x;
  if (e<NE){
    int d = dst[e];
    int p = ptr[d] + atomicAdd(&cur[d],1);
    cidx[p] = e;
  }
}

// runtime input-dtype detector (fp32 low-halfword exponents ~uniform; bf16 ~always in-range)
__global__ void k_detect(const u16* x, int* flag){
  __shared__ int cnt;
  if (threadIdx.x==0) cnt=0;
  __syncthreads();
  u16 u = x[threadIdx.x*2];
  int e = (u>>7)&0xff;
  if (e>=100 && e<=135) atomicAdd(&cnt,1);
  __syncthreads();
  if (threadIdx.x==0) *flag = (cnt>=128) ? 1 : 0;
}

__launch_bounds__(256)
__global__ void k_bnstats(const float* z, const void* bng, const void* bnb, float* st, const int* dflag){
  int dt = *dflag;
  int c = threadIdx.x;
  float sm=0.f, sq=0.f;
  for (int g=0; g<NG; ++g){ float v = z[(size_t)g*256+c]; sm+=v; sq+=v*v; }
  float mu = sm*(1.f/(float)NG);
  float var = sq*(1.f/(float)NG) - mu*mu;
  float rs = rsqrtf(fmaxf(var,0.f)+1e-5f);
  float sc = rs*rg(bng,c,dt);
  st[c] = sc;
  st[256+c] = rg(bnb,c,dt) - mu*sc;
}

// OUTPUT fp32 (confirmed: finite ref-scale error under fp32 writes)
__global__ void k_pred(const float* z, const float* st, const void* pw, const void* pb, float* out, const int* dflag){
  int dt = *dflag;
  int g = blockIdx.x*256+threadIdx.x;
  if (g>=NG) return;
  float acc = rg(pb,0,dt);
  for (int c=0;c<256;c++) acc += (z[(size_t)g*256+c]*st[c] + st[256+c])*rg(pw,c,dt);
  out[g]=acc;
}

extern "C" void kernel_launch(void* const* d_in, const int* in_sizes, int n_in,
                              void* d_out, int out_size, void* d_ws, size_t ws_size,
                              hipStream_t stream)
{
  const void* X    =d_in[0];
  const void* EA   =d_in[1];
  const void* NW   =d_in[2];
  const void* NB   =d_in[3];
  const void* NGa  =d_in[4];
  const void* NBt  =d_in[5];
  const void* EW   =d_in[6];
  const void* EB   =d_in[7];
  const void* EGa  =d_in[8];
  const void* EBt  =d_in[9];
  const void* LW   =d_in[10];
  const void* LB   =d_in[11];
  const void* LGa  =d_in[12];
  const void* LBt  =d_in[13];
  const void* NUW  =d_in[14];
  const void* NUB  =d_in[15];
  const void* NNG  =d_in[16];
  const void* NNB  =d_in[17];
  const void* EUW  =d_in[18];
  const void* EUB  =d_in[19];
  const void* BOOST=d_in[20];
  const void* BIHW_F=d_in[21];
  const void* BHHW_F=d_in[22];
  const void* BIHB_F=d_in[23];
  const void* BHHB_F=d_in[24];
  const void* BIHW_B=d_in[25];
  const void* BHHW_B=d_in[26];
  const void* BIHB_B=d_in[27];
  const void* BHHB_B=d_in[28];
  const void* PW   =d_in[29];
  const void* PB   =d_in[30];
  const void* PG   =d_in[31];
  const void* PBt  =d_in[32];
  const void* FW   =d_in[33];
  const void* FB   =d_in[34];
  const void* FG   =d_in[35];
  const void* FBt  =d_in[36];
  const void* RIHW_F=d_in[37];
  const void* RHHW_F=d_in[38];
  const void* RIHB_F=d_in[39];
  const void* RHHB_F=d_in[40];
  const void* RIHW_B=d_in[41];
  const void* RHHW_B=d_in[42];
  const void* RIHB_B=d_in[43];
  const void* RHHB_B=d_in[44];
  const void* BNG  =d_in[45];
  const void* BNB  =d_in[46];
  const void* PRW  =d_in[47];
  const void* PRB  =d_in[48];
  const int* EIDX =(const int*)d_in[49];
  const int* DST  = EIDX + NE;

  // ---- Workspace (EXACT r9 proven map; peak < 118MB).
  //      bigws (>=137MB): hx2 at [120,136) survives init->merge. ----
  char* ws=(char*)d_ws;
  const size_t MB = 1048576;
  int*   csrp =(int*)  (ws + 0);
  int*   csrc =(int*)  (ws + 135168);
  int*   csri =(int*)  (ws + 266240);
  float* zbuf =(float*)(ws + 790528);
  float* stats=(float*)(ws + 1314816);
  int*   dflag=(int*)  (ws + 1316864);
  float* wbgf =(float*)(ws + 2*MB);
  float* wbgb = wbgf + 49536;
  float* wrgf = wbgb + 49536;
  float* wrgb = wrgf + 49536;
  float* hv   =(float*)(ws + 6*MB);          // [6,22)
  u16*   he0  =(u16*)  (ws + 22*MB);         // [22,54), dead after last edge
  float* he   =(float*)(ws + 54*MB);         // [54,118), dead after k_gather
  float* mfin =(float*)(ws + 22*MB);         // aliases he0 (dead)
  u16*   gif  =(u16*)  (ws + 54*MB);         // aliases he (dead), [54,78)
  u16*   gib  =(u16*)  (ws + 78*MB);         // [78,102)
  u16*   oseq =(u16*)  (ws + 6*MB);          // aliases hv (dead after boost-GI)
  float* hv2  =(float*)(ws + 38*MB);         // [38,54)
  float* fout =(float*)(ws + 54*MB);         // aliases gif (dead), [54,70)
  u16*   gif_r=(u16*)  (ws + 70*MB);         // [70,94)
  u16*   gib_r=(u16*)  (ws + 94*MB);         // [94,118)

  const bool bigws = (ws_size >= (size_t)137*MB);
  float* hx2 = bigws ? (float*)(ws + 120*MB)   // [120,136): survives init->merge
                     : (float*)(ws + 6*MB);    // fallback: computed just before merge

  k_detect<<<dim3(1),dim3(256),0,stream>>>((const u16*)X, dflag);

  // pre-convert recurrent GRU weights to fp32 (one merged launch)
  k_cvt4<<<dim3(194,4),dim3(256),0,stream>>>(
      BHHW_F,BHHB_F, BHHW_B,BHHB_B, RHHW_F,RHHB_F, RHHW_B,RHHB_B,
      wbgf, wbgb, wrgf, wrgb, dflag);

  // CSR over dst
  hipMemsetAsync(csrc, 0, 131072, stream);
  k_count<<<dim3(512),dim3(256),0,stream>>>(DST, csrc);
  k_scan<<<dim3(1),dim3(1024),0,stream>>>(csrc, csrp);
  hipMemsetAsync(csrc, 0, 131072, stream);
  k_fill<<<dim3(512),dim3(256),0,stream>>>(DST, csrp, csrc, csri);

  // init embeddings
  if (bigws){
    // fused dual-LN: X staged ONCE -> hv (NW, LN+ReLU) and hx2 (LW, LN)
    k_dense<A_XF,E_LN_RELU,1,2,32><<<dim3(1024),dim3(256),0,stream>>>(X,LGa,LBt,
        nullptr,nullptr,nullptr,nullptr, NW,LW,0, NB,LB,NGa,NBt,0, nullptr,nullptr,
        hv,(u16*)hx2,nullptr, dflag, 133,133,HD,0);
  } else {
    k_dense<A_XF,E_LN_RELU,3,1,32><<<dim3(1024),dim3(256),0,stream>>>(X,nullptr,nullptr,
        nullptr,nullptr,nullptr,nullptr, NW,nullptr,0, NB,nullptr,NGa,NBt,0, nullptr,nullptr,
        hv,nullptr,nullptr, dflag, 133,133,HD,0);
  }
  k_dense<A_XF,E_LN_RELU_DUAL,1,1,32><<<dim3(4096),dim3(256),0,stream>>>(EA,nullptr,nullptr,
      nullptr,nullptr,nullptr,nullptr, EW,nullptr,0, EB,nullptr,EGa,EBt,0, nullptr,nullptr,
      he,he0,nullptr, dflag, 14,14,HD,0);

  // message passing (msg: 32-row; edge: 32-row)
  for (int s=0;s<5;s++){
    k_dense<A_MSG,E_RESID_LN,4,1,32><<<dim3(1024),dim3(256),0,stream>>>(hv,he,nullptr,
        nullptr,csrp,csri,nullptr, NUW,nullptr,s*32768, NUB,nullptr,NNG,NNB,s*128,
        hv,nullptr, hv,nullptr,nullptr, dflag, 256,HD,HD,0);
    k_dense<A_EDGE,E_HE0_RELU,2,1,32><<<dim3(4096),dim3(256),0,stream>>>(hv,he,nullptr,
        DST,nullptr,nullptr,nullptr, EUW,nullptr,s*16384, EUB,nullptr,nullptr,nullptr,s*128,
        nullptr,he0, he,nullptr,nullptr, dflag, 128,HD,HD,0);
  }
  k_gather<<<dim3(NN/4),dim3(256),0,stream>>>(he, csrp, csri, mfin);

  // boost GRU input-side gates: ONE launch, 6 weight segments (frozen geometry)
  k_dense<A_BOOST,E_GI,1,6,64><<<dim3(512),dim3(256),0,stream>>>(hv,nullptr,nullptr,
      nullptr,nullptr,nullptr,BOOST, BIHW_F,BIHW_B,0, BIHB_F,BIHB_B,nullptr,nullptr,0,
      nullptr,nullptr, nullptr,gif,gib, dflag, 128,HD,384,0);
  k_gru<<<dim3(128,2),dim3(384),0,stream>>>(gif, gib, wbgf, wbgb, oseq, zbuf, 1);

  // proj + (hx2 if not fused) + final merge (32-row LN tiles)
  k_dense<A_B16,E_LN_RELU_TANH,4,1,32><<<dim3(1024),dim3(256),0,stream>>>(oseq,nullptr,nullptr,
      nullptr,nullptr,nullptr,nullptr, PW,nullptr,0, PB,nullptr,PG,PBt,0, nullptr,nullptr,
      hv2,nullptr,nullptr, dflag, 256,256,HD,0);
  if (!bigws){
    k_dense<A_XF,E_LN,3,1,32><<<dim3(1024),dim3(256),0,stream>>>(X,nullptr,nullptr,
        nullptr,nullptr,nullptr,nullptr, LW,nullptr,0, LB,nullptr,LGa,LBt,0, nullptr,nullptr,
        hx2,nullptr,nullptr, dflag, 133,133,HD,0);
  }
  k_dense<A_C3,E_LN_RELU,6,1,32><<<dim3(1024),dim3(256),0,stream>>>(hv2,mfin,hx2,
      nullptr,nullptr,nullptr,nullptr, FW,nullptr,0, FB,nullptr,FG,FBt,0, nullptr,nullptr,
      fout,nullptr,nullptr, dflag, 384,HD,HD,0);

  // readout GRU gates (ONE launch, 6 segments) + GRU
  k_dense<A_F32,E_GI,1,6,64><<<dim3(512),dim3(256),0,stream>>>(fout,nullptr,nullptr,
      nullptr,nullptr,nullptr,nullptr, RIHW_F,RIHW_B,0, RIHB_F,RIHB_B,nullptr,nullptr,0,
      nullptr,nullptr, nullptr,gif_r,gib_r, dflag, 128,HD,384,0);
  k_gru<<<dim3(128,2),dim3(384),0,stream>>>(gif_r, gib_r, wrgf, wrgb, oseq, zbuf, 0);

  // BN + prediction
  k_bnstats<<<dim3(1),dim3(256),0,stream>>>(zbuf, BNG, BNB, stats, dflag);
  k_pred<<<dim3(2),dim3(256),0,stream>>>(zbuf, stats, PRW, PRB, (float*)d_out, dflag);

  (void)in_sizes; (void)n_in; (void)out_size;
}